// Round 16
// baseline (585.007 us; speedup 1.0000x reference)
//
#include <hip/hip_runtime.h>
#include <hip/hip_bf16.h>

#define NB 8
#define CC 256
#define OO 768
#define LL 512
#define VV 25
#define PP 3
#define KM 768
#define NKC 24          // K-chunks of 32
#define LT 4            // l's per block

typedef __attribute__((ext_vector_type(8))) short short8v;
typedef __attribute__((ext_vector_type(4))) float float4v;
typedef __attribute__((ext_vector_type(4))) int int4v;

__device__ inline unsigned pk2(float a, float b){
    __hip_bfloat16 ha = __float2bfloat16(a), hb = __float2bfloat16(b);
    unsigned short ua = *(unsigned short*)&ha, ub = *(unsigned short*)&hb;
    return (unsigned)ua | ((unsigned)ub << 16);
}

// ---------------------------------------------------------------------------
// W -> fragment-ordered bf16 layout in d_ws (validated rounds 6-15).
// ---------------------------------------------------------------------------
__global__ __launch_bounds__(256) void wperm_kernel(const float* __restrict__ W,
                                                    __hip_bfloat16* __restrict__ Wp) {
    int idx = blockIdx.x * 256 + threadIdx.x;
    if (idx >= OO * CC) return;
    int j    = idx & 7;
    int lane = (idx >> 3) & 63;
    int mt   = (idx >> 9) & 3;
    int wm   = (idx >> 11) & 3;
    int kc   = idx >> 13;                    // 0..23
    int c = wm * 64 + mt * 16 + (lane & 15);
    int k = kc * 32 + ((lane >> 4) << 3) + j;
    int cib = k / 192;
    int r = k - cib * 192;
    int p = r >> 6;
    int ci = cib * 64 + (r & 63);
    Wp[idx] = __float2bfloat16(W[(p * 256 + c) * 256 + ci]);
}

// ---------------------------------------------------------------------------
// Round-12 phase code, restructured for 48 KB LDS -> 3 blocks/CU:
// Zb shrunk 6->3 chunks; each cib = [stage][bar] then 2x { zgen-half [bar]
// consume 3 chunks [bar] }. Epilogue in four 64-c quarters (OT 25.6 KB).
// Same per-block work and traffic as r12; +50% resident blocks for TLP.
// ---------------------------------------------------------------------------
__global__ __launch_bounds__(512, 6) void fused_main_kernel(
    const float* __restrict__ x,
    const __hip_bfloat16* __restrict__ Wp,
    const float* __restrict__ A,
    const float* __restrict__ gamma, const float* __restrict__ beta,
    const float* __restrict__ mean, const float* __restrict__ var,
    float* __restrict__ out)
{
    __shared__ __align__(16) char smem[49152];
    __hip_bfloat16* const ZB0  = (__hip_bfloat16*)smem;            // 3*4096 elems (24576 B)
    __hip_bfloat16* const XSH  = (__hip_bfloat16*)(smem + 24576);  // 256*32 (16384 B)
    __hip_bfloat16* const A2T  = (__hip_bfloat16*)(smem + 40960);  // 3*32*32 (6144 B)
    float*          const SCSH = (float*)(smem + 47104);           // 512 (2048 B)
    float*          const OT   = (float*)smem;                     // 6400 f32 (epilogue)

    const int tid  = threadIdx.x;
    const int lane = tid & 63, wid = tid >> 6;
    const int lcol = lane & 15, grp = lane >> 4;
    const int bid0 = blockIdx.x;
    const int swz = (bid0 & 7) * 128 + (bid0 >> 3);   // XCD-contiguous chunks
    const int n  = swz >> 7;
    const int l0 = (swz & 127) * LT;
    const int wm = wid >> 1, wn = wid & 1;       // main-GEMM wave grid 4M x 2N
    const int l_z = wid >> 1, mt_z = wid & 1;    // zgen wave roles

    // ---- prologue: zero pads, BN coefs ----
    {
        int4v z = {0, 0, 0, 0};
        ((int4v*)XSH)[tid] = z;
        ((int4v*)XSH)[tid + 512] = z;
        if (tid < 384) ((int4v*)A2T)[tid] = z;
        int c = tid & 255;
        float sc = gamma[c] * rsqrtf(var[c] + 1e-5f);
        if (tid < 256) SCSH[tid] = sc;
        else           SCSH[tid] = beta[c] - mean[c] * sc;
    }
    __syncthreads();
    // A^T scatter: a2t[p*32 + w][v ^ swz]  (validated r4-r15)
    for (int idx = tid; idx < PP * VV * VV; idx += 512) {
        int p = idx / 625, r = idx - p * 625, v = r / 25, w = r - v * 25;
        int R = p * 32 + w;
        int e = (((v >> 3) ^ ((R >> 1) & 3)) << 3) | (v & 7);
        A2T[R * 32 + e] = __float2bfloat16(A[idx]);
    }

    auto stage_xs = [&](int cib) {
        for (int cc = tid; cc < 1600; cc += 512) {
            int ci6 = cc / 25, v = cc - ci6 * 25;
            const float* xp = x + ((size_t)(n * CC + cib * 64 + ci6) * LL) * VV + v;
            float rbuf[12];
            #pragma unroll
            for (int j = 0; j < 12; ++j) {
                int lj = l0 - 8 + j;
                rbuf[j] = (lj >= 0) ? xp[(size_t)lj * VV] : 0.f;
            }
            float wsv = 0.f;
            #pragma unroll
            for (int j = 0; j < 9; ++j) wsv += rbuf[j];
            #pragma unroll
            for (int i = 0; i < LT; ++i) {
                int R = ci6 * 4 + i;
                int e = (((v >> 3) ^ ((R >> 2) & 3)) << 3) | (v & 7);
                XSH[R * 32 + e] = __float2bfloat16(wsv);
                if (i < LT - 1) wsv += rbuf[9 + i] - rbuf[i];
            }
        }
    };

    // zgen for 3 chunks (half of a cib): j = half*3 + jj, (p,h) = (j>>1, j&1)
    auto zgen_half = [&](int half) {
        short8v az[2];
        #pragma unroll
        for (int h = 0; h < 2; ++h) {
            int ci6 = h * 32 + mt_z * 16 + lcol;
            int R = ci6 * 4 + l_z;
            az[h] = *(const short8v*)&XSH[R * 32 + ((grp ^ ((R >> 2) & 3)) << 3)];
        }
        #pragma unroll
        for (int jj = 0; jj < 3; ++jj) {
            int j = half * 3 + jj;
            int p = j >> 1, h = j & 1;
            #pragma unroll
            for (int wt = 0; wt < 2; ++wt) {
                int R2 = p * 32 + wt * 16 + lcol;
                short8v bz = *(const short8v*)&A2T[R2 * 32 + ((grp ^ ((R2 >> 1) & 3)) << 3)];
                float4v zc = {0.f, 0.f, 0.f, 0.f};
                zc = __builtin_amdgcn_mfma_f32_16x16x32_bf16(az[h], bz, zc, 0, 0, 0);
                int R3 = l_z * 32 + wt * 16 + lcol;
                int eb = (mt_z * 2 + (grp >> 1)) ^ ((R3 >> 1) & 3);
                unsigned* dst = (unsigned*)&ZB0[jj * 4096 + R3 * 32 + (eb << 3) + ((grp & 1) << 2)];
                dst[0] = pk2(zc[0], zc[1]);
                dst[1] = pk2(zc[2], zc[3]);
            }
        }
    };

    float4v acc[4][4];
    #pragma unroll
    for (int i = 0; i < 4; ++i)
        #pragma unroll
        for (int j = 0; j < 4; ++j) acc[i][j] = (float4v){0.f, 0.f, 0.f, 0.f};

    const __hip_bfloat16* afbase = Wp + ((size_t)(wm * 4) * 64 + lane) * 8;

    #pragma unroll 1
    for (int cib = 0; cib < 4; ++cib) {
        __syncthreads();                 // prev Zb consumed; XSH free
        stage_xs(cib);
        __syncthreads();

        #pragma unroll
        for (int half = 0; half < 2; ++half) {
            zgen_half(half);             // XSH -> Zb[0..2]
            __syncthreads();

            // barrier-free consumption of 3 chunks, compiler-scheduled
            #pragma unroll
            for (int jj = 0; jj < 3; ++jj) {
                const int kc = cib * 6 + half * 3 + jj;
                short8v af[4];
                {
                    const __hip_bfloat16* ap = afbase + (size_t)kc * 8192;
                    #pragma unroll
                    for (int mt = 0; mt < 4; ++mt)
                        af[mt] = *(const short8v*)(ap + mt * 512);
                }
                short8v bf[4];
                #pragma unroll
                for (int nt = 0; nt < 4; ++nt) {
                    int R3 = wn * 64 + nt * 16 + lcol;
                    bf[nt] = *(const short8v*)&ZB0[jj * 4096 + R3 * 32 + ((grp ^ ((R3 >> 1) & 3)) << 3)];
                }
                #pragma unroll
                for (int mt = 0; mt < 4; ++mt)
                    #pragma unroll
                    for (int nt = 0; nt < 4; ++nt)
                        acc[mt][nt] = __builtin_amdgcn_mfma_f32_16x16x32_bf16(af[mt], bf[nt], acc[mt][nt], 0, 0, 0);
            }
            if (half == 0) __syncthreads();  // Zb about to be overwritten
        }
    }

    // ---- epilogue: LDS roundtrip, four 64-c quarters, float4-coalesced ----
    #pragma unroll 1
    for (int q = 0; q < 4; ++q) {
        __syncthreads();                 // region free / prev quarter copied
        if (wm == q) {
            #pragma unroll
            for (int mt = 0; mt < 4; ++mt) {
                #pragma unroll
                for (int nt = 0; nt < 4; ++nt) {
                    int lw = wn * 64 + nt * 16;
                    int w = lw & 31;
                    int l = lw >> 5;
                    int wl = w + lcol;
                    if (wl < VV) {
                        #pragma unroll
                        for (int r = 0; r < 4; ++r) {
                            int c_l = mt * 16 + grp * 4 + r;              // 0..63
                            int c   = q * 64 + c_l;
                            float val = fmaf(acc[mt][nt][r], SCSH[c], SCSH[256 + c]);
                            OT[c_l * 100 + l * 25 + wl] = fmaxf(val, 0.f);
                        }
                    }
                }
            }
        }
        __syncthreads();
        // coalesced: 64 c * 25 float4 = 1600 float4; 400B contiguous per c
        const size_t gbase = ((size_t)(n * CC + q * 64) * LL + l0) * VV;
        for (int i = tid; i < 1600; i += 512) {
            int c_l = i / 25, qd = i - c_l * 25;
            float4v v4 = *(float4v*)&OT[c_l * 100 + qd * 4];
            size_t ad = gbase + (size_t)c_l * (LL * VV) + qd * 4;
            float4v r4 = *(const float4v*)&x[ad];
            float4v o4;
            o4[0] = fmaxf(v4[0] + r4[0], 0.f);
            o4[1] = fmaxf(v4[1] + r4[1], 0.f);
            o4[2] = fmaxf(v4[2] + r4[2], 0.f);
            o4[3] = fmaxf(v4[3] + r4[3], 0.f);
            *(float4v*)&out[ad] = o4;
        }
    }
}

// ===========================================================================
// Fallback path (ws too small): round-1/2 proven kernels (in-place on d_out)
// ===========================================================================
__global__ __launch_bounds__(256) void wsum_kernel(const float* __restrict__ x,
                                                   float* __restrict__ xs) {
    const int CHUNKS = 8;
    int t = blockIdx.x * 256 + threadIdx.x;
    if (t >= NB * CC * VV * CHUNKS) return;
    int v = t % VV;
    int r = t / VV;
    int chunk = r % CHUNKS;
    int nc = r / CHUNKS;
    int l0 = chunk * (LL / CHUNKS);
    const float* xp = x  + (size_t)nc * (LL * VV) + v;
    float*       op = xs + (size_t)nc * (LL * VV) + v;
    float ring[8];
    float run = 0.f;
    #pragma unroll
    for (int k = 0; k < 8; ++k) {
        int j = l0 - 8 + k;
        float val = (j >= 0) ? xp[j * VV] : 0.f;
        ring[k] = val; run += val;
    }
    for (int base = l0; base < l0 + LL / CHUNKS; base += 8) {
        #pragma unroll
        for (int k = 0; k < 8; ++k) {
            int l = base + k;
            float val = xp[l * VV];
            float o = run + val;
            op[l * VV] = o;
            run = o - ring[k];
            ring[k] = val;
        }
    }
}

__global__ __launch_bounds__(256) void fused_fallback_kernel(
    const float* xs, const float* __restrict__ x, const float* __restrict__ W,
    const float* __restrict__ A,
    const float* __restrict__ gamma, const float* __restrict__ beta,
    const float* __restrict__ mean, const float* __restrict__ var,
    float* out)
{
    __shared__ float xshf[CC][28];
    const int bid = blockIdx.x;
    const int n = bid >> 9;
    const int l = bid & 511;
    const int tid = threadIdx.x;
    const size_t nbase = (size_t)n * CC * LL * VV;
    for (int k = tid; k < CC * VV; k += 256) {
        int ci = k / VV, v = k - ci * VV;
        xshf[ci][v] = xs[nbase + (size_t)ci * (LL * VV) + (size_t)l * VV + v];
    }
    __syncthreads();
    const int c = tid;
    float Y[PP * VV];
    #pragma unroll
    for (int i = 0; i < PP * VV; ++i) Y[i] = 0.f;
    const float* Wpr = W + c * 256;
    #pragma unroll 1
    for (int ci = 0; ci < CC; ++ci) {
        float xv[VV];
        #pragma unroll
        for (int v = 0; v < VV; ++v) xv[v] = xshf[ci][v];
        float w0 = Wpr[ci], w1 = Wpr[65536 + ci], w2 = Wpr[131072 + ci];
        #pragma unroll
        for (int v = 0; v < VV; ++v) Y[v]          = fmaf(w0, xv[v], Y[v]);
        #pragma unroll
        for (int v = 0; v < VV; ++v) Y[VV + v]     = fmaf(w1, xv[v], Y[VV + v]);
        #pragma unroll
        for (int v = 0; v < VV; ++v) Y[2 * VV + v] = fmaf(w2, xv[v], Y[2 * VV + v]);
    }
    float o[VV];
    #pragma unroll
    for (int w = 0; w < VV; ++w) o[w] = 0.f;
    #pragma unroll
    for (int p = 0; p < PP; ++p)
        #pragma unroll
        for (int v = 0; v < VV; ++v) {
            float y = Y[p * VV + v];
            const float* Ap = A + (p * VV + v) * VV;
            #pragma unroll
            for (int w = 0; w < VV; ++w) o[w] = fmaf(y, Ap[w], o[w]);
        }
    float sc = gamma[c] * rsqrtf(var[c] + 1e-5f);
    float sh = beta[c] - mean[c] * sc;
    const float* resp = x   + nbase + (size_t)c * (LL * VV) + (size_t)l * VV;
    float*       outp = out + nbase + (size_t)c * (LL * VV) + (size_t)l * VV;
    #pragma unroll
    for (int w = 0; w < VV; ++w) {
        float t2 = fmaf(o[w], sc, sh);
        t2 = fmaxf(t2, 0.f);
        t2 = fmaxf(t2 + resp[w], 0.f);
        outp[w] = t2;
    }
}

extern "C" void kernel_launch(void* const* d_in, const int* in_sizes, int n_in,
                              void* d_out, int out_size, void* d_ws, size_t ws_size,
                              hipStream_t stream) {
    const float* x  = (const float*)d_in[0];
    const float* W  = (const float*)d_in[1];
    const float* A  = (const float*)d_in[2];
    const float* gm = (const float*)d_in[3];
    const float* bt = (const float*)d_in[4];
    const float* mn = (const float*)d_in[5];
    const float* vr = (const float*)d_in[6];
    float* out = (float*)d_out;

    if (ws_size >= (size_t)(OO * CC * sizeof(__hip_bfloat16))) {
        __hip_bfloat16* Wp = (__hip_bfloat16*)d_ws;
        wperm_kernel<<<dim3((OO * CC + 255) / 256), dim3(256), 0, stream>>>(W, Wp);
        fused_main_kernel<<<dim3(NB * (LL / LT)), dim3(512), 0, stream>>>(
            x, Wp, A, gm, bt, mn, vr, out);
    } else {
        const int threadsA = NB * CC * VV * 8;
        wsum_kernel<<<dim3((threadsA + 255) / 256), dim3(256), 0, stream>>>(x, out);
        fused_fallback_kernel<<<dim3(NB * LL), dim3(256), 0, stream>>>(
            out, x, W, A, gm, bt, mn, vr, out);
    }
}

// Round 17
// 102.857 us; speedup vs baseline: 5.6876x; 5.6876x over previous
//
#include <hip/hip_runtime.h>
#include <hip/hip_bf16.h>

#define NB 8
#define CC 256
#define OO 768
#define LL 512
#define VV 25
#define PP 3
#define KM 768
#define NKC 24          // K-chunks of 32
#define LT 4            // l's per block

typedef __attribute__((ext_vector_type(8))) short short8v;
typedef __attribute__((ext_vector_type(4))) float float4v;
typedef __attribute__((ext_vector_type(4))) int int4v;

__device__ inline unsigned pk2(float a, float b){
    __hip_bfloat16 ha = __float2bfloat16(a), hb = __float2bfloat16(b);
    unsigned short ua = *(unsigned short*)&ha, ub = *(unsigned short*)&hb;
    return (unsigned)ua | ((unsigned)ub << 16);
}

// ---------------------------------------------------------------------------
// W -> fragment-ordered bf16 layout in d_ws (validated rounds 6-16):
//   idx = (((kc*4 + wm)*4 + mt)*64 + lane)*8 + j
//   holds W'[c][k], c = wm*64+mt*16+(lane&15), k = kc*32+(lane>>4)*8+j
//   W'[c][k] = W[(p*256+c)*256 + ci], k = cib*192+p*64+ci6, ci = cib*64+ci6.
// ---------------------------------------------------------------------------
__global__ __launch_bounds__(256) void wperm_kernel(const float* __restrict__ W,
                                                    __hip_bfloat16* __restrict__ Wp) {
    int idx = blockIdx.x * 256 + threadIdx.x;
    if (idx >= OO * CC) return;
    int j    = idx & 7;
    int lane = (idx >> 3) & 63;
    int mt   = (idx >> 9) & 3;
    int wm   = (idx >> 11) & 3;
    int kc   = idx >> 13;                    // 0..23
    int c = wm * 64 + mt * 16 + (lane & 15);
    int k = kc * 32 + ((lane >> 4) << 3) + j;
    int cib = k / 192;
    int r = k - cib * 192;
    int p = r >> 6;
    int ci = cib * 64 + (r & 63);
    Wp[idx] = __float2bfloat16(W[(p * 256 + c) * 256 + ci]);
}

// ---------------------------------------------------------------------------
// Round-12 kernel (best measured: 103 us headline / 130 us dispatch).
// Fused: window-sum staging + bulk Z-gen per cib + barrier-free 6-chunk MFMA
// consumption + LDS-roundtrip coalesced epilogue (BN/relu/residual/relu).
// Block = (n, 4 l's), 512 threads / 8 waves, 72 KB LDS, 2 blocks/CU.
// NOTE (r16 lesson): do NOT raise min-waves in __launch_bounds__ — acc[4][4]
// needs 64 regs; capping below ~120 spills accumulators to scratch (WRITE
// 105 MB -> 1.35 GB, 5x slowdown).
// ---------------------------------------------------------------------------
__global__ __launch_bounds__(512, 4) void fused_main_kernel(
    const float* __restrict__ x,
    const __hip_bfloat16* __restrict__ Wp,
    const float* __restrict__ A,
    const float* __restrict__ gamma, const float* __restrict__ beta,
    const float* __restrict__ mean, const float* __restrict__ var,
    float* __restrict__ out)
{
    __shared__ __align__(16) char smem[73728];
    __hip_bfloat16* const ZB0  = (__hip_bfloat16*)smem;            // 6*4096 elems
    __hip_bfloat16* const XSH  = (__hip_bfloat16*)(smem + 49152);  // 256*32
    __hip_bfloat16* const A2T  = (__hip_bfloat16*)(smem + 65536);  // 3*32*32
    float*          const SCSH = (float*)(smem + 71680);           // 512
    float*          const OT   = (float*)smem;                     // 12800 f32 (epilogue)

    const int tid  = threadIdx.x;
    const int lane = tid & 63, wid = tid >> 6;
    const int lcol = lane & 15, grp = lane >> 4;
    const int bid0 = blockIdx.x;
    const int swz = (bid0 & 7) * 128 + (bid0 >> 3);   // XCD-contiguous chunks
    const int n  = swz >> 7;
    const int l0 = (swz & 127) * LT;
    const int wm = wid >> 1, wn = wid & 1;       // main-GEMM wave grid 4M x 2N
    const int l_z = wid >> 1, mt_z = wid & 1;    // zgen wave roles

    // ---- prologue: zero pads, BN coefs ----
    {
        int4v z = {0, 0, 0, 0};
        ((int4v*)XSH)[tid] = z;
        ((int4v*)XSH)[tid + 512] = z;
        if (tid < 384) ((int4v*)A2T)[tid] = z;
        int c = tid & 255;
        float sc = gamma[c] * rsqrtf(var[c] + 1e-5f);
        if (tid < 256) SCSH[tid] = sc;
        else           SCSH[tid] = beta[c] - mean[c] * sc;
    }
    __syncthreads();
    // A^T scatter: a2t[p*32 + w][v ^ swz]  (validated r4-r16)
    for (int idx = tid; idx < PP * VV * VV; idx += 512) {
        int p = idx / 625, r = idx - p * 625, v = r / 25, w = r - v * 25;
        int R = p * 32 + w;
        int e = (((v >> 3) ^ ((R >> 1) & 3)) << 3) | (v & 7);
        A2T[R * 32 + e] = __float2bfloat16(A[idx]);
    }

    auto stage_xs = [&](int cib) {
        for (int cc = tid; cc < 1600; cc += 512) {
            int ci6 = cc / 25, v = cc - ci6 * 25;
            const float* xp = x + ((size_t)(n * CC + cib * 64 + ci6) * LL) * VV + v;
            float rbuf[12];
            #pragma unroll
            for (int j = 0; j < 12; ++j) {
                int lj = l0 - 8 + j;
                rbuf[j] = (lj >= 0) ? xp[(size_t)lj * VV] : 0.f;
            }
            float wsv = 0.f;
            #pragma unroll
            for (int j = 0; j < 9; ++j) wsv += rbuf[j];
            #pragma unroll
            for (int i = 0; i < LT; ++i) {
                int R = ci6 * 4 + i;
                int e = (((v >> 3) ^ ((R >> 2) & 3)) << 3) | (v & 7);
                XSH[R * 32 + e] = __float2bfloat16(wsv);
                if (i < LT - 1) wsv += rbuf[9 + i] - rbuf[i];
            }
        }
    };

    // bulk Z-gen: all 6 chunks of this cib (j = p*2 + h, matching kc%6)
    auto zgen_all = [&]() {
        short8v az[2];
        #pragma unroll
        for (int h = 0; h < 2; ++h) {
            int ci6 = h * 32 + mt_z * 16 + lcol;
            int R = ci6 * 4 + l_z;
            az[h] = *(const short8v*)&XSH[R * 32 + ((grp ^ ((R >> 2) & 3)) << 3)];
        }
        #pragma unroll
        for (int p = 0; p < PP; ++p) {
            #pragma unroll
            for (int wt = 0; wt < 2; ++wt) {
                int R2 = p * 32 + wt * 16 + lcol;
                short8v bz = *(const short8v*)&A2T[R2 * 32 + ((grp ^ ((R2 >> 1) & 3)) << 3)];
                #pragma unroll
                for (int h = 0; h < 2; ++h) {
                    float4v zc = {0.f, 0.f, 0.f, 0.f};
                    zc = __builtin_amdgcn_mfma_f32_16x16x32_bf16(az[h], bz, zc, 0, 0, 0);
                    int R3 = l_z * 32 + wt * 16 + lcol;
                    int eb = (mt_z * 2 + (grp >> 1)) ^ ((R3 >> 1) & 3);
                    unsigned* dst = (unsigned*)&ZB0[(p * 2 + h) * 4096 + R3 * 32 + (eb << 3) + ((grp & 1) << 2)];
                    dst[0] = pk2(zc[0], zc[1]);
                    dst[1] = pk2(zc[2], zc[3]);
                }
            }
        }
    };

    float4v acc[4][4];
    #pragma unroll
    for (int i = 0; i < 4; ++i)
        #pragma unroll
        for (int j = 0; j < 4; ++j) acc[i][j] = (float4v){0.f, 0.f, 0.f, 0.f};

    const __hip_bfloat16* afbase = Wp + ((size_t)(wm * 4) * 64 + lane) * 8;

    #pragma unroll 1
    for (int cib = 0; cib < 4; ++cib) {
        __syncthreads();                 // prev-cib Zb consumed; a2t/xsh-pads visible
        stage_xs(cib);
        __syncthreads();
        zgen_all();
        __syncthreads();

        // barrier-free consumption: 6 chunks, compiler-scheduled
        #pragma unroll
        for (int j = 0; j < 6; ++j) {
            const int kc = cib * 6 + j;
            short8v af[4];
            {
                const __hip_bfloat16* ap = afbase + (size_t)kc * 8192;
                #pragma unroll
                for (int mt = 0; mt < 4; ++mt)
                    af[mt] = *(const short8v*)(ap + mt * 512);
            }
            short8v bf[4];
            #pragma unroll
            for (int nt = 0; nt < 4; ++nt) {
                int R3 = wn * 64 + nt * 16 + lcol;
                bf[nt] = *(const short8v*)&ZB0[j * 4096 + R3 * 32 + ((grp ^ ((R3 >> 1) & 3)) << 3)];
            }
            #pragma unroll
            for (int mt = 0; mt < 4; ++mt)
                #pragma unroll
                for (int nt = 0; nt < 4; ++nt)
                    acc[mt][nt] = __builtin_amdgcn_mfma_f32_16x16x32_bf16(af[mt], bf[nt], acc[mt][nt], 0, 0, 0);
        }
    }

    // ---- epilogue: LDS roundtrip, two 128-c halves, float4-coalesced I/O ----
    const int halfsel = wm >> 1;
    #pragma unroll 1
    for (int h = 0; h < 2; ++h) {
        __syncthreads();
        if (halfsel == h) {
            const int c_l0 = (wm & 1) * 64;
            #pragma unroll
            for (int mt = 0; mt < 4; ++mt) {
                #pragma unroll
                for (int nt = 0; nt < 4; ++nt) {
                    int lw = wn * 64 + nt * 16;
                    int w = lw & 31;
                    int l = lw >> 5;
                    int wl = w + lcol;
                    if (wl < VV) {
                        #pragma unroll
                        for (int r = 0; r < 4; ++r) {
                            int c_l = c_l0 + mt * 16 + grp * 4 + r;       // 0..127
                            int c   = h * 128 + c_l;
                            float val = fmaf(acc[mt][nt][r], SCSH[c], SCSH[256 + c]);
                            OT[c_l * 100 + l * 25 + wl] = fmaxf(val, 0.f);
                        }
                    }
                }
            }
        }
        __syncthreads();
        const size_t gbase = ((size_t)(n * CC + h * 128) * LL + l0) * VV;
        for (int i = tid; i < 3200; i += 512) {
            int c_l = i / 25, q = i - c_l * 25;
            float4v v4 = *(float4v*)&OT[c_l * 100 + q * 4];
            size_t ad = gbase + (size_t)c_l * (LL * VV) + q * 4;
            float4v r4 = *(const float4v*)&x[ad];
            float4v o4;
            o4[0] = fmaxf(v4[0] + r4[0], 0.f);
            o4[1] = fmaxf(v4[1] + r4[1], 0.f);
            o4[2] = fmaxf(v4[2] + r4[2], 0.f);
            o4[3] = fmaxf(v4[3] + r4[3], 0.f);
            *(float4v*)&out[ad] = o4;
        }
    }
}

// ===========================================================================
// Fallback path (ws too small): round-1/2 proven kernels (in-place on d_out)
// ===========================================================================
__global__ __launch_bounds__(256) void wsum_kernel(const float* __restrict__ x,
                                                   float* __restrict__ xs) {
    const int CHUNKS = 8;
    int t = blockIdx.x * 256 + threadIdx.x;
    if (t >= NB * CC * VV * CHUNKS) return;
    int v = t % VV;
    int r = t / VV;
    int chunk = r % CHUNKS;
    int nc = r / CHUNKS;
    int l0 = chunk * (LL / CHUNKS);
    const float* xp = x  + (size_t)nc * (LL * VV) + v;
    float*       op = xs + (size_t)nc * (LL * VV) + v;
    float ring[8];
    float run = 0.f;
    #pragma unroll
    for (int k = 0; k < 8; ++k) {
        int j = l0 - 8 + k;
        float val = (j >= 0) ? xp[j * VV] : 0.f;
        ring[k] = val; run += val;
    }
    for (int base = l0; base < l0 + LL / CHUNKS; base += 8) {
        #pragma unroll
        for (int k = 0; k < 8; ++k) {
            int l = base + k;
            float val = xp[l * VV];
            float o = run + val;
            op[l * VV] = o;
            run = o - ring[k];
            ring[k] = val;
        }
    }
}

__global__ __launch_bounds__(256) void fused_fallback_kernel(
    const float* xs, const float* __restrict__ x, const float* __restrict__ W,
    const float* __restrict__ A,
    const float* __restrict__ gamma, const float* __restrict__ beta,
    const float* __restrict__ mean, const float* __restrict__ var,
    float* out)
{
    __shared__ float xshf[CC][28];
    const int bid = blockIdx.x;
    const int n = bid >> 9;
    const int l = bid & 511;
    const int tid = threadIdx.x;
    const size_t nbase = (size_t)n * CC * LL * VV;
    for (int k = tid; k < CC * VV; k += 256) {
        int ci = k / VV, v = k - ci * VV;
        xshf[ci][v] = xs[nbase + (size_t)ci * (LL * VV) + (size_t)l * VV + v];
    }
    __syncthreads();
    const int c = tid;
    float Y[PP * VV];
    #pragma unroll
    for (int i = 0; i < PP * VV; ++i) Y[i] = 0.f;
    const float* Wpr = W + c * 256;
    #pragma unroll 1
    for (int ci = 0; ci < CC; ++ci) {
        float xv[VV];
        #pragma unroll
        for (int v = 0; v < VV; ++v) xv[v] = xshf[ci][v];
        float w0 = Wpr[ci], w1 = Wpr[65536 + ci], w2 = Wpr[131072 + ci];
        #pragma unroll
        for (int v = 0; v < VV; ++v) Y[v]          = fmaf(w0, xv[v], Y[v]);
        #pragma unroll
        for (int v = 0; v < VV; ++v) Y[VV + v]     = fmaf(w1, xv[v], Y[VV + v]);
        #pragma unroll
        for (int v = 0; v < VV; ++v) Y[2 * VV + v] = fmaf(w2, xv[v], Y[2 * VV + v]);
    }
    float o[VV];
    #pragma unroll
    for (int w = 0; w < VV; ++w) o[w] = 0.f;
    #pragma unroll
    for (int p = 0; p < PP; ++p)
        #pragma unroll
        for (int v = 0; v < VV; ++v) {
            float y = Y[p * VV + v];
            const float* Ap = A + (p * VV + v) * VV;
            #pragma unroll
            for (int w = 0; w < VV; ++w) o[w] = fmaf(y, Ap[w], o[w]);
        }
    float sc = gamma[c] * rsqrtf(var[c] + 1e-5f);
    float sh = beta[c] - mean[c] * sc;
    const float* resp = x   + nbase + (size_t)c * (LL * VV) + (size_t)l * VV;
    float*       outp = out + nbase + (size_t)c * (LL * VV) + (size_t)l * VV;
    #pragma unroll
    for (int w = 0; w < VV; ++w) {
        float t2 = fmaf(o[w], sc, sh);
        t2 = fmaxf(t2, 0.f);
        t2 = fmaxf(t2 + resp[w], 0.f);
        outp[w] = t2;
    }
}

extern "C" void kernel_launch(void* const* d_in, const int* in_sizes, int n_in,
                              void* d_out, int out_size, void* d_ws, size_t ws_size,
                              hipStream_t stream) {
    const float* x  = (const float*)d_in[0];
    const float* W  = (const float*)d_in[1];
    const float* A  = (const float*)d_in[2];
    const float* gm = (const float*)d_in[3];
    const float* bt = (const float*)d_in[4];
    const float* mn = (const float*)d_in[5];
    const float* vr = (const float*)d_in[6];
    float* out = (float*)d_out;

    if (ws_size >= (size_t)(OO * CC * sizeof(__hip_bfloat16))) {
        __hip_bfloat16* Wp = (__hip_bfloat16*)d_ws;
        wperm_kernel<<<dim3((OO * CC + 255) / 256), dim3(256), 0, stream>>>(W, Wp);
        fused_main_kernel<<<dim3(NB * (LL / LT)), dim3(512), 0, stream>>>(
            x, Wp, A, gm, bt, mn, vr, out);
    } else {
        const int threadsA = NB * CC * VV * 8;
        wsum_kernel<<<dim3((threadsA + 255) / 256), dim3(256), 0, stream>>>(x, out);
        fused_fallback_kernel<<<dim3(NB * LL), dim3(256), 0, stream>>>(
            out, x, W, A, gm, bt, mn, vr, out);
    }
}

// Round 18
// 99.876 us; speedup vs baseline: 5.8573x; 1.0298x over previous
//
#include <hip/hip_runtime.h>
#include <hip/hip_bf16.h>

#define NB 8
#define CC 256
#define OO 768
#define LL 512
#define VV 25
#define PP 3
#define KM 768
#define NKC 24          // K-chunks of 32
#define LT 4            // l's per block

typedef __attribute__((ext_vector_type(8))) short short8v;
typedef __attribute__((ext_vector_type(4))) float float4v;
typedef __attribute__((ext_vector_type(4))) int int4v;

__device__ inline unsigned pk2(float a, float b){
    __hip_bfloat16 ha = __float2bfloat16(a), hb = __float2bfloat16(b);
    unsigned short ua = *(unsigned short*)&ha, ub = *(unsigned short*)&hb;
    return (unsigned)ua | ((unsigned)ub << 16);
}

// ---------------------------------------------------------------------------
// W -> fragment-ordered bf16 layout in d_ws, 8M x 1N wave grid (af dedup):
//   idx = (((kc*8 + wm)*2 + mt)*64 + lane)*8 + j
//   holds W'[c][k], c = wm*32 + mt*16 + (lane&15), k = kc*32 + (lane>>4)*8 + j
//   W'[c][k] = W[(p*256+c)*256 + ci], k = cib*192+p*64+ci6, ci = cib*64+ci6.
// Each of the 8 waves owns a unique wm -> every af fragment loaded ONCE per
// block (r12's 4Mx2N grid loaded each twice).
// ---------------------------------------------------------------------------
__global__ __launch_bounds__(256) void wperm_kernel(const float* __restrict__ W,
                                                    __hip_bfloat16* __restrict__ Wp) {
    int idx = blockIdx.x * 256 + threadIdx.x;
    if (idx >= OO * CC) return;
    int j    = idx & 7;
    int lane = (idx >> 3) & 63;
    int mt   = (idx >> 9) & 1;
    int wm   = (idx >> 10) & 7;
    int kc   = idx >> 13;                    // 0..23
    int c = wm * 32 + mt * 16 + (lane & 15);
    int k = kc * 32 + ((lane >> 4) << 3) + j;
    int cib = k / 192;
    int r = k - cib * 192;
    int p = r >> 6;
    int ci = cib * 64 + (r & 63);
    Wp[idx] = __float2bfloat16(W[(p * 256 + c) * 256 + ci]);
}

// ---------------------------------------------------------------------------
// Round-12 structure with 8M x 1N consume grid (af-dedup). All other phases
// (staging, zgen, Zb layout, barriers, epilogue geometry) byte-identical.
// Block = (n, 4 l's), 512 threads / 8 waves, 72 KB LDS, 2 blocks/CU.
// NOTE (r16 lesson): do NOT raise min-waves in __launch_bounds__ — acc needs
// 64 regs; capping below ~120 total spills accumulators to scratch (5x).
// bf reads are grouped 2x4 to keep VGPR under the 128-reg occupancy bin.
// ---------------------------------------------------------------------------
__global__ __launch_bounds__(512, 4) void fused_main_kernel(
    const float* __restrict__ x,
    const __hip_bfloat16* __restrict__ Wp,
    const float* __restrict__ A,
    const float* __restrict__ gamma, const float* __restrict__ beta,
    const float* __restrict__ mean, const float* __restrict__ var,
    float* __restrict__ out)
{
    __shared__ __align__(16) char smem[73728];
    __hip_bfloat16* const ZB0  = (__hip_bfloat16*)smem;            // 6*4096 elems
    __hip_bfloat16* const XSH  = (__hip_bfloat16*)(smem + 49152);  // 256*32
    __hip_bfloat16* const A2T  = (__hip_bfloat16*)(smem + 65536);  // 3*32*32
    float*          const SCSH = (float*)(smem + 71680);           // 512
    float*          const OT   = (float*)smem;                     // 12800 f32 (epilogue)

    const int tid  = threadIdx.x;
    const int lane = tid & 63, wid = tid >> 6;
    const int lcol = lane & 15, grp = lane >> 4;
    const int bid0 = blockIdx.x;
    const int swz = (bid0 & 7) * 128 + (bid0 >> 3);   // XCD-contiguous chunks
    const int n  = swz >> 7;
    const int l0 = (swz & 127) * LT;
    const int wm = wid;                          // 8M x 1N: wave owns 32 c's
    const int l_z = wid >> 1, mt_z = wid & 1;    // zgen wave roles (unchanged)

    // ---- prologue: zero pads, BN coefs ----
    {
        int4v z = {0, 0, 0, 0};
        ((int4v*)XSH)[tid] = z;
        ((int4v*)XSH)[tid + 512] = z;
        if (tid < 384) ((int4v*)A2T)[tid] = z;
        int c = tid & 255;
        float sc = gamma[c] * rsqrtf(var[c] + 1e-5f);
        if (tid < 256) SCSH[tid] = sc;
        else           SCSH[tid] = beta[c] - mean[c] * sc;
    }
    __syncthreads();
    // A^T scatter: a2t[p*32 + w][v ^ swz]  (validated r4-r17)
    for (int idx = tid; idx < PP * VV * VV; idx += 512) {
        int p = idx / 625, r = idx - p * 625, v = r / 25, w = r - v * 25;
        int R = p * 32 + w;
        int e = (((v >> 3) ^ ((R >> 1) & 3)) << 3) | (v & 7);
        A2T[R * 32 + e] = __float2bfloat16(A[idx]);
    }

    auto stage_xs = [&](int cib) {
        for (int cc = tid; cc < 1600; cc += 512) {
            int ci6 = cc / 25, v = cc - ci6 * 25;
            const float* xp = x + ((size_t)(n * CC + cib * 64 + ci6) * LL) * VV + v;
            float rbuf[12];
            #pragma unroll
            for (int j = 0; j < 12; ++j) {
                int lj = l0 - 8 + j;
                rbuf[j] = (lj >= 0) ? xp[(size_t)lj * VV] : 0.f;
            }
            float wsv = 0.f;
            #pragma unroll
            for (int j = 0; j < 9; ++j) wsv += rbuf[j];
            #pragma unroll
            for (int i = 0; i < LT; ++i) {
                int R = ci6 * 4 + i;
                int e = (((v >> 3) ^ ((R >> 2) & 3)) << 3) | (v & 7);
                XSH[R * 32 + e] = __float2bfloat16(wsv);
                if (i < LT - 1) wsv += rbuf[9 + i] - rbuf[i];
            }
        }
    };

    // bulk Z-gen: all 6 chunks of this cib (j = p*2 + h, matching kc%6)
    auto zgen_all = [&]() {
        short8v az[2];
        #pragma unroll
        for (int h = 0; h < 2; ++h) {
            int ci6 = h * 32 + mt_z * 16 + lcol;
            int R = ci6 * 4 + l_z;
            az[h] = *(const short8v*)&XSH[R * 32 + ((grp ^ ((R >> 2) & 3)) << 3)];
        }
        #pragma unroll
        for (int p = 0; p < PP; ++p) {
            #pragma unroll
            for (int wt = 0; wt < 2; ++wt) {
                int R2 = p * 32 + wt * 16 + lcol;
                short8v bz = *(const short8v*)&A2T[R2 * 32 + ((grp ^ ((R2 >> 1) & 3)) << 3)];
                #pragma unroll
                for (int h = 0; h < 2; ++h) {
                    float4v zc = {0.f, 0.f, 0.f, 0.f};
                    zc = __builtin_amdgcn_mfma_f32_16x16x32_bf16(az[h], bz, zc, 0, 0, 0);
                    int R3 = l_z * 32 + wt * 16 + lcol;
                    int eb = (mt_z * 2 + (grp >> 1)) ^ ((R3 >> 1) & 3);
                    unsigned* dst = (unsigned*)&ZB0[(p * 2 + h) * 4096 + R3 * 32 + (eb << 3) + ((grp & 1) << 2)];
                    dst[0] = pk2(zc[0], zc[1]);
                    dst[1] = pk2(zc[2], zc[3]);
                }
            }
        }
    };

    float4v acc[2][8];
    #pragma unroll
    for (int i = 0; i < 2; ++i)
        #pragma unroll
        for (int j = 0; j < 8; ++j) acc[i][j] = (float4v){0.f, 0.f, 0.f, 0.f};

    // af base: per (wm): 1024 elems per kc-slice of 8192
    const __hip_bfloat16* afbase = Wp + (size_t)wm * 1024 + (size_t)lane * 8;

    #pragma unroll 1
    for (int cib = 0; cib < 4; ++cib) {
        __syncthreads();                 // prev-cib Zb consumed; a2t/xsh-pads visible
        stage_xs(cib);
        __syncthreads();
        zgen_all();
        __syncthreads();

        // barrier-free consumption: 6 chunks, compiler-scheduled
        #pragma unroll
        for (int j = 0; j < 6; ++j) {
            const int kc = cib * 6 + j;
            short8v af[2];
            {
                const __hip_bfloat16* ap = afbase + (size_t)kc * 8192;
                #pragma unroll
                for (int mt = 0; mt < 2; ++mt)
                    af[mt] = *(const short8v*)(ap + mt * 512);
            }
            // grouped bf (2x4) keeps register pressure under the 128-bin
            #pragma unroll
            for (int g = 0; g < 2; ++g) {
                short8v bf[4];
                #pragma unroll
                for (int q = 0; q < 4; ++q) {
                    int R3 = (g * 4 + q) * 16 + lcol;
                    bf[q] = *(const short8v*)&ZB0[j * 4096 + R3 * 32 + ((grp ^ ((R3 >> 1) & 3)) << 3)];
                }
                #pragma unroll
                for (int mt = 0; mt < 2; ++mt)
                    #pragma unroll
                    for (int q = 0; q < 4; ++q)
                        acc[mt][g * 4 + q] = __builtin_amdgcn_mfma_f32_16x16x32_bf16(af[mt], bf[q], acc[mt][g * 4 + q], 0, 0, 0);
            }
        }
    }

    // ---- epilogue: LDS roundtrip, two 128-c halves, float4-coalesced I/O ----
    const int halfsel = wm >> 2;           // waves 0-3: c<128, waves 4-7: c>=128
    #pragma unroll 1
    for (int h = 0; h < 2; ++h) {
        __syncthreads();
        if (halfsel == h) {
            const int c_l0 = (wm & 3) * 32;
            #pragma unroll
            for (int mt = 0; mt < 2; ++mt) {
                #pragma unroll
                for (int nt = 0; nt < 8; ++nt) {
                    int lw = nt * 16;
                    int w = lw & 31;
                    int l = lw >> 5;
                    int wl = w + lcol;
                    if (wl < VV) {
                        #pragma unroll
                        for (int r = 0; r < 4; ++r) {
                            int c_l = c_l0 + mt * 16 + grp * 4 + r;       // 0..127
                            int c   = h * 128 + c_l;
                            float val = fmaf(acc[mt][nt][r], SCSH[c], SCSH[256 + c]);
                            OT[c_l * 100 + l * 25 + wl] = fmaxf(val, 0.f);
                        }
                    }
                }
            }
        }
        __syncthreads();
        const size_t gbase = ((size_t)(n * CC + h * 128) * LL + l0) * VV;
        for (int i = tid; i < 3200; i += 512) {
            int c_l = i / 25, q = i - c_l * 25;
            float4v v4 = *(float4v*)&OT[c_l * 100 + q * 4];
            size_t ad = gbase + (size_t)c_l * (LL * VV) + q * 4;
            float4v r4 = *(const float4v*)&x[ad];
            float4v o4;
            o4[0] = fmaxf(v4[0] + r4[0], 0.f);
            o4[1] = fmaxf(v4[1] + r4[1], 0.f);
            o4[2] = fmaxf(v4[2] + r4[2], 0.f);
            o4[3] = fmaxf(v4[3] + r4[3], 0.f);
            *(float4v*)&out[ad] = o4;
        }
    }
}

// ===========================================================================
// Fallback path (ws too small): round-1/2 proven kernels (in-place on d_out)
// ===========================================================================
__global__ __launch_bounds__(256) void wsum_kernel(const float* __restrict__ x,
                                                   float* __restrict__ xs) {
    const int CHUNKS = 8;
    int t = blockIdx.x * 256 + threadIdx.x;
    if (t >= NB * CC * VV * CHUNKS) return;
    int v = t % VV;
    int r = t / VV;
    int chunk = r % CHUNKS;
    int nc = r / CHUNKS;
    int l0 = chunk * (LL / CHUNKS);
    const float* xp = x  + (size_t)nc * (LL * VV) + v;
    float*       op = xs + (size_t)nc * (LL * VV) + v;
    float ring[8];
    float run = 0.f;
    #pragma unroll
    for (int k = 0; k < 8; ++k) {
        int j = l0 - 8 + k;
        float val = (j >= 0) ? xp[j * VV] : 0.f;
        ring[k] = val; run += val;
    }
    for (int base = l0; base < l0 + LL / CHUNKS; base += 8) {
        #pragma unroll
        for (int k = 0; k < 8; ++k) {
            int l = base + k;
            float val = xp[l * VV];
            float o = run + val;
            op[l * VV] = o;
            run = o - ring[k];
            ring[k] = val;
        }
    }
}

__global__ __launch_bounds__(256) void fused_fallback_kernel(
    const float* xs, const float* __restrict__ x, const float* __restrict__ W,
    const float* __restrict__ A,
    const float* __restrict__ gamma, const float* __restrict__ beta,
    const float* __restrict__ mean, const float* __restrict__ var,
    float* out)
{
    __shared__ float xshf[CC][28];
    const int bid = blockIdx.x;
    const int n = bid >> 9;
    const int l = bid & 511;
    const int tid = threadIdx.x;
    const size_t nbase = (size_t)n * CC * LL * VV;
    for (int k = tid; k < CC * VV; k += 256) {
        int ci = k / VV, v = k - ci * VV;
        xshf[ci][v] = xs[nbase + (size_t)ci * (LL * VV) + (size_t)l * VV + v];
    }
    __syncthreads();
    const int c = tid;
    float Y[PP * VV];
    #pragma unroll
    for (int i = 0; i < PP * VV; ++i) Y[i] = 0.f;
    const float* Wpr = W + c * 256;
    #pragma unroll 1
    for (int ci = 0; ci < CC; ++ci) {
        float xv[VV];
        #pragma unroll
        for (int v = 0; v < VV; ++v) xv[v] = xshf[ci][v];
        float w0 = Wpr[ci], w1 = Wpr[65536 + ci], w2 = Wpr[131072 + ci];
        #pragma unroll
        for (int v = 0; v < VV; ++v) Y[v]          = fmaf(w0, xv[v], Y[v]);
        #pragma unroll
        for (int v = 0; v < VV; ++v) Y[VV + v]     = fmaf(w1, xv[v], Y[VV + v]);
        #pragma unroll
        for (int v = 0; v < VV; ++v) Y[2 * VV + v] = fmaf(w2, xv[v], Y[2 * VV + v]);
    }
    float o[VV];
    #pragma unroll
    for (int w = 0; w < VV; ++w) o[w] = 0.f;
    #pragma unroll
    for (int p = 0; p < PP; ++p)
        #pragma unroll
        for (int v = 0; v < VV; ++v) {
            float y = Y[p * VV + v];
            const float* Ap = A + (p * VV + v) * VV;
            #pragma unroll
            for (int w = 0; w < VV; ++w) o[w] = fmaf(y, Ap[w], o[w]);
        }
    float sc = gamma[c] * rsqrtf(var[c] + 1e-5f);
    float sh = beta[c] - mean[c] * sc;
    const float* resp = x   + nbase + (size_t)c * (LL * VV) + (size_t)l * VV;
    float*       outp = out + nbase + (size_t)c * (LL * VV) + (size_t)l * VV;
    #pragma unroll
    for (int w = 0; w < VV; ++w) {
        float t2 = fmaf(o[w], sc, sh);
        t2 = fmaxf(t2, 0.f);
        t2 = fmaxf(t2 + resp[w], 0.f);
        outp[w] = t2;
    }
}

extern "C" void kernel_launch(void* const* d_in, const int* in_sizes, int n_in,
                              void* d_out, int out_size, void* d_ws, size_t ws_size,
                              hipStream_t stream) {
    const float* x  = (const float*)d_in[0];
    const float* W  = (const float*)d_in[1];
    const float* A  = (const float*)d_in[2];
    const float* gm = (const float*)d_in[3];
    const float* bt = (const float*)d_in[4];
    const float* mn = (const float*)d_in[5];
    const float* vr = (const float*)d_in[6];
    float* out = (float*)d_out;

    if (ws_size >= (size_t)(OO * CC * sizeof(__hip_bfloat16))) {
        __hip_bfloat16* Wp = (__hip_bfloat16*)d_ws;
        wperm_kernel<<<dim3((OO * CC + 255) / 256), dim3(256), 0, stream>>>(W, Wp);
        fused_main_kernel<<<dim3(NB * (LL / LT)), dim3(512), 0, stream>>>(
            x, Wp, A, gm, bt, mn, vr, out);
    } else {
        const int threadsA = NB * CC * VV * 8;
        wsum_kernel<<<dim3((threadsA + 255) / 256), dim3(256), 0, stream>>>(x, out);
        fused_fallback_kernel<<<dim3(NB * LL), dim3(256), 0, stream>>>(
            out, x, W, A, gm, bt, mn, vr, out);
    }
}

// Round 19
// 96.827 us; speedup vs baseline: 6.0418x; 1.0315x over previous
//
#include <hip/hip_runtime.h>
#include <hip/hip_bf16.h>

#define NB 8
#define CC 256
#define OO 768
#define LL 512
#define VV 25
#define PP 3
#define KM 768
#define NKC 24          // K-chunks of 32
#define LT 4            // l's per block

typedef __attribute__((ext_vector_type(8))) short short8v;
typedef __attribute__((ext_vector_type(4))) float float4v;
typedef __attribute__((ext_vector_type(4))) int int4v;

__device__ inline unsigned pk2(float a, float b){
    __hip_bfloat16 ha = __float2bfloat16(a), hb = __float2bfloat16(b);
    unsigned short ua = *(unsigned short*)&ha, ub = *(unsigned short*)&hb;
    return (unsigned)ua | ((unsigned)ub << 16);
}

// ---------------------------------------------------------------------------
// W -> fragment-ordered bf16 layout in d_ws, 8M x 1N wave grid (af dedup):
//   idx = (((kc*8 + wm)*2 + mt)*64 + lane)*8 + j
//   holds W'[c][k], c = wm*32 + mt*16 + (lane&15), k = kc*32 + (lane>>4)*8 + j
//   W'[c][k] = W[(p*256+c)*256 + ci], k = cib*192+p*64+ci6, ci = cib*64+ci6.
// ---------------------------------------------------------------------------
__global__ __launch_bounds__(256) void wperm_kernel(const float* __restrict__ W,
                                                    __hip_bfloat16* __restrict__ Wp) {
    int idx = blockIdx.x * 256 + threadIdx.x;
    if (idx >= OO * CC) return;
    int j    = idx & 7;
    int lane = (idx >> 3) & 63;
    int mt   = (idx >> 9) & 1;
    int wm   = (idx >> 10) & 7;
    int kc   = idx >> 13;                    // 0..23
    int c = wm * 32 + mt * 16 + (lane & 15);
    int k = kc * 32 + ((lane >> 4) << 3) + j;
    int cib = k / 192;
    int r = k - cib * 192;
    int p = r >> 6;
    int ci = cib * 64 + (r & 63);
    Wp[idx] = __float2bfloat16(W[(p * 256 + c) * 256 + ci]);
}

// ---------------------------------------------------------------------------
// Round-18 structure (8M x 1N af-dedup, best measured: 99.9 us headline)
// + af prefetch for chunks 0-1 hoisted above zgen (their L2 latency was the
// only load latency the compiler could not hide across the barrier).
// Block = (n, 4 l's), 512 threads / 8 waves, 72 KB LDS, 2 blocks/CU.
// NOTE (r16 lesson): never raise min-waves in __launch_bounds__ — acc needs
// 64 regs; capping below ~120 total spills accumulators to scratch (5x).
// ---------------------------------------------------------------------------
__global__ __launch_bounds__(512, 4) void fused_main_kernel(
    const float* __restrict__ x,
    const __hip_bfloat16* __restrict__ Wp,
    const float* __restrict__ A,
    const float* __restrict__ gamma, const float* __restrict__ beta,
    const float* __restrict__ mean, const float* __restrict__ var,
    float* __restrict__ out)
{
    __shared__ __align__(16) char smem[73728];
    __hip_bfloat16* const ZB0  = (__hip_bfloat16*)smem;            // 6*4096 elems
    __hip_bfloat16* const XSH  = (__hip_bfloat16*)(smem + 49152);  // 256*32
    __hip_bfloat16* const A2T  = (__hip_bfloat16*)(smem + 65536);  // 3*32*32
    float*          const SCSH = (float*)(smem + 71680);           // 512
    float*          const OT   = (float*)smem;                     // 12800 f32 (epilogue)

    const int tid  = threadIdx.x;
    const int lane = tid & 63, wid = tid >> 6;
    const int lcol = lane & 15, grp = lane >> 4;
    const int bid0 = blockIdx.x;
    const int swz = (bid0 & 7) * 128 + (bid0 >> 3);   // XCD-contiguous chunks
    const int n  = swz >> 7;
    const int l0 = (swz & 127) * LT;
    const int wm = wid;                          // 8M x 1N: wave owns 32 c's
    const int l_z = wid >> 1, mt_z = wid & 1;    // zgen wave roles

    // ---- prologue: zero pads, BN coefs ----
    {
        int4v z = {0, 0, 0, 0};
        ((int4v*)XSH)[tid] = z;
        ((int4v*)XSH)[tid + 512] = z;
        if (tid < 384) ((int4v*)A2T)[tid] = z;
        int c = tid & 255;
        float sc = gamma[c] * rsqrtf(var[c] + 1e-5f);
        if (tid < 256) SCSH[tid] = sc;
        else           SCSH[tid] = beta[c] - mean[c] * sc;
    }
    __syncthreads();
    // A^T scatter: a2t[p*32 + w][v ^ swz]  (validated r4-r18)
    for (int idx = tid; idx < PP * VV * VV; idx += 512) {
        int p = idx / 625, r = idx - p * 625, v = r / 25, w = r - v * 25;
        int R = p * 32 + w;
        int e = (((v >> 3) ^ ((R >> 1) & 3)) << 3) | (v & 7);
        A2T[R * 32 + e] = __float2bfloat16(A[idx]);
    }

    auto stage_xs = [&](int cib) {
        for (int cc = tid; cc < 1600; cc += 512) {
            int ci6 = cc / 25, v = cc - ci6 * 25;
            const float* xp = x + ((size_t)(n * CC + cib * 64 + ci6) * LL) * VV + v;
            float rbuf[12];
            #pragma unroll
            for (int j = 0; j < 12; ++j) {
                int lj = l0 - 8 + j;
                rbuf[j] = (lj >= 0) ? xp[(size_t)lj * VV] : 0.f;
            }
            float wsv = 0.f;
            #pragma unroll
            for (int j = 0; j < 9; ++j) wsv += rbuf[j];
            #pragma unroll
            for (int i = 0; i < LT; ++i) {
                int R = ci6 * 4 + i;
                int e = (((v >> 3) ^ ((R >> 2) & 3)) << 3) | (v & 7);
                XSH[R * 32 + e] = __float2bfloat16(wsv);
                if (i < LT - 1) wsv += rbuf[9 + i] - rbuf[i];
            }
        }
    };

    // bulk Z-gen: all 6 chunks of this cib (j = p*2 + h, matching kc%6)
    auto zgen_all = [&]() {
        short8v az[2];
        #pragma unroll
        for (int h = 0; h < 2; ++h) {
            int ci6 = h * 32 + mt_z * 16 + lcol;
            int R = ci6 * 4 + l_z;
            az[h] = *(const short8v*)&XSH[R * 32 + ((grp ^ ((R >> 2) & 3)) << 3)];
        }
        #pragma unroll
        for (int p = 0; p < PP; ++p) {
            #pragma unroll
            for (int wt = 0; wt < 2; ++wt) {
                int R2 = p * 32 + wt * 16 + lcol;
                short8v bz = *(const short8v*)&A2T[R2 * 32 + ((grp ^ ((R2 >> 1) & 3)) << 3)];
                #pragma unroll
                for (int h = 0; h < 2; ++h) {
                    float4v zc = {0.f, 0.f, 0.f, 0.f};
                    zc = __builtin_amdgcn_mfma_f32_16x16x32_bf16(az[h], bz, zc, 0, 0, 0);
                    int R3 = l_z * 32 + wt * 16 + lcol;
                    int eb = (mt_z * 2 + (grp >> 1)) ^ ((R3 >> 1) & 3);
                    unsigned* dst = (unsigned*)&ZB0[(p * 2 + h) * 4096 + R3 * 32 + (eb << 3) + ((grp & 1) << 2)];
                    dst[0] = pk2(zc[0], zc[1]);
                    dst[1] = pk2(zc[2], zc[3]);
                }
            }
        }
    };

    float4v acc[2][8];
    #pragma unroll
    for (int i = 0; i < 2; ++i)
        #pragma unroll
        for (int j = 0; j < 8; ++j) acc[i][j] = (float4v){0.f, 0.f, 0.f, 0.f};

    const __hip_bfloat16* afbase = Wp + (size_t)wm * 1024 + (size_t)lane * 8;

    #pragma unroll 1
    for (int cib = 0; cib < 4; ++cib) {
        __syncthreads();                 // prev-cib Zb consumed; a2t/xsh-pads visible
        stage_xs(cib);
        __syncthreads();

        // hoisted af prefetch for chunks 0-1: L2 latency hides under zgen;
        // the compiler's vmcnt(0) drain before the next barrier completes them.
        short8v afp[2][2];
        #pragma unroll
        for (int jj = 0; jj < 2; ++jj) {
            const __hip_bfloat16* ap = afbase + (size_t)(cib * 6 + jj) * 8192;
            afp[jj][0] = *(const short8v*)(ap);
            afp[jj][1] = *(const short8v*)(ap + 512);
        }

        zgen_all();
        __syncthreads();

        // barrier-free consumption: 6 chunks, compiler-scheduled
        #pragma unroll
        for (int j = 0; j < 6; ++j) {
            const int kc = cib * 6 + j;
            short8v af[2];
            if (j < 2) {                 // compile-time (unrolled) — rule #20 safe
                af[0] = afp[j][0];
                af[1] = afp[j][1];
            } else {
                const __hip_bfloat16* ap = afbase + (size_t)kc * 8192;
                af[0] = *(const short8v*)(ap);
                af[1] = *(const short8v*)(ap + 512);
            }
            // grouped bf (2x4) keeps register pressure under the 128-bin
            #pragma unroll
            for (int g = 0; g < 2; ++g) {
                short8v bf[4];
                #pragma unroll
                for (int q = 0; q < 4; ++q) {
                    int R3 = (g * 4 + q) * 16 + lcol;
                    bf[q] = *(const short8v*)&ZB0[j * 4096 + R3 * 32 + ((grp ^ ((R3 >> 1) & 3)) << 3)];
                }
                #pragma unroll
                for (int mt = 0; mt < 2; ++mt)
                    #pragma unroll
                    for (int q = 0; q < 4; ++q)
                        acc[mt][g * 4 + q] = __builtin_amdgcn_mfma_f32_16x16x32_bf16(af[mt], bf[q], acc[mt][g * 4 + q], 0, 0, 0);
            }
        }
    }

    // ---- epilogue: LDS roundtrip, two 128-c halves, float4-coalesced I/O ----
    const int halfsel = wm >> 2;           // waves 0-3: c<128, waves 4-7: c>=128
    #pragma unroll 1
    for (int h = 0; h < 2; ++h) {
        __syncthreads();
        if (halfsel == h) {
            const int c_l0 = (wm & 3) * 32;
            #pragma unroll
            for (int mt = 0; mt < 2; ++mt) {
                #pragma unroll
                for (int nt = 0; nt < 8; ++nt) {
                    int lw = nt * 16;
                    int w = lw & 31;
                    int l = lw >> 5;
                    int wl = w + lcol;
                    if (wl < VV) {
                        #pragma unroll
                        for (int r = 0; r < 4; ++r) {
                            int c_l = c_l0 + mt * 16 + grp * 4 + r;       // 0..127
                            int c   = h * 128 + c_l;
                            float val = fmaf(acc[mt][nt][r], SCSH[c], SCSH[256 + c]);
                            OT[c_l * 100 + l * 25 + wl] = fmaxf(val, 0.f);
                        }
                    }
                }
            }
        }
        __syncthreads();
        const size_t gbase = ((size_t)(n * CC + h * 128) * LL + l0) * VV;
        for (int i = tid; i < 3200; i += 512) {
            int c_l = i / 25, q = i - c_l * 25;
            float4v v4 = *(float4v*)&OT[c_l * 100 + q * 4];
            size_t ad = gbase + (size_t)c_l * (LL * VV) + q * 4;
            float4v r4 = *(const float4v*)&x[ad];
            float4v o4;
            o4[0] = fmaxf(v4[0] + r4[0], 0.f);
            o4[1] = fmaxf(v4[1] + r4[1], 0.f);
            o4[2] = fmaxf(v4[2] + r4[2], 0.f);
            o4[3] = fmaxf(v4[3] + r4[3], 0.f);
            *(float4v*)&out[ad] = o4;
        }
    }
}

// ===========================================================================
// Fallback path (ws too small): round-1/2 proven kernels (in-place on d_out)
// ===========================================================================
__global__ __launch_bounds__(256) void wsum_kernel(const float* __restrict__ x,
                                                   float* __restrict__ xs) {
    const int CHUNKS = 8;
    int t = blockIdx.x * 256 + threadIdx.x;
    if (t >= NB * CC * VV * CHUNKS) return;
    int v = t % VV;
    int r = t / VV;
    int chunk = r % CHUNKS;
    int nc = r / CHUNKS;
    int l0 = chunk * (LL / CHUNKS);
    const float* xp = x  + (size_t)nc * (LL * VV) + v;
    float*       op = xs + (size_t)nc * (LL * VV) + v;
    float ring[8];
    float run = 0.f;
    #pragma unroll
    for (int k = 0; k < 8; ++k) {
        int j = l0 - 8 + k;
        float val = (j >= 0) ? xp[j * VV] : 0.f;
        ring[k] = val; run += val;
    }
    for (int base = l0; base < l0 + LL / CHUNKS; base += 8) {
        #pragma unroll
        for (int k = 0; k < 8; ++k) {
            int l = base + k;
            float val = xp[l * VV];
            float o = run + val;
            op[l * VV] = o;
            run = o - ring[k];
            ring[k] = val;
        }
    }
}

__global__ __launch_bounds__(256) void fused_fallback_kernel(
    const float* xs, const float* __restrict__ x, const float* __restrict__ W,
    const float* __restrict__ A,
    const float* __restrict__ gamma, const float* __restrict__ beta,
    const float* __restrict__ mean, const float* __restrict__ var,
    float* out)
{
    __shared__ float xshf[CC][28];
    const int bid = blockIdx.x;
    const int n = bid >> 9;
    const int l = bid & 511;
    const int tid = threadIdx.x;
    const size_t nbase = (size_t)n * CC * LL * VV;
    for (int k = tid; k < CC * VV; k += 256) {
        int ci = k / VV, v = k - ci * VV;
        xshf[ci][v] = xs[nbase + (size_t)ci * (LL * VV) + (size_t)l * VV + v];
    }
    __syncthreads();
    const int c = tid;
    float Y[PP * VV];
    #pragma unroll
    for (int i = 0; i < PP * VV; ++i) Y[i] = 0.f;
    const float* Wpr = W + c * 256;
    #pragma unroll 1
    for (int ci = 0; ci < CC; ++ci) {
        float xv[VV];
        #pragma unroll
        for (int v = 0; v < VV; ++v) xv[v] = xshf[ci][v];
        float w0 = Wpr[ci], w1 = Wpr[65536 + ci], w2 = Wpr[131072 + ci];
        #pragma unroll
        for (int v = 0; v < VV; ++v) Y[v]          = fmaf(w0, xv[v], Y[v]);
        #pragma unroll
        for (int v = 0; v < VV; ++v) Y[VV + v]     = fmaf(w1, xv[v], Y[VV + v]);
        #pragma unroll
        for (int v = 0; v < VV; ++v) Y[2 * VV + v] = fmaf(w2, xv[v], Y[2 * VV + v]);
    }
    float o[VV];
    #pragma unroll
    for (int w = 0; w < VV; ++w) o[w] = 0.f;
    #pragma unroll
    for (int p = 0; p < PP; ++p)
        #pragma unroll
        for (int v = 0; v < VV; ++v) {
            float y = Y[p * VV + v];
            const float* Ap = A + (p * VV + v) * VV;
            #pragma unroll
            for (int w = 0; w < VV; ++w) o[w] = fmaf(y, Ap[w], o[w]);
        }
    float sc = gamma[c] * rsqrtf(var[c] + 1e-5f);
    float sh = beta[c] - mean[c] * sc;
    const float* resp = x   + nbase + (size_t)c * (LL * VV) + (size_t)l * VV;
    float*       outp = out + nbase + (size_t)c * (LL * VV) + (size_t)l * VV;
    #pragma unroll
    for (int w = 0; w < VV; ++w) {
        float t2 = fmaf(o[w], sc, sh);
        t2 = fmaxf(t2, 0.f);
        t2 = fmaxf(t2 + resp[w], 0.f);
        outp[w] = t2;
    }
}

extern "C" void kernel_launch(void* const* d_in, const int* in_sizes, int n_in,
                              void* d_out, int out_size, void* d_ws, size_t ws_size,
                              hipStream_t stream) {
    const float* x  = (const float*)d_in[0];
    const float* W  = (const float*)d_in[1];
    const float* A  = (const float*)d_in[2];
    const float* gm = (const float*)d_in[3];
    const float* bt = (const float*)d_in[4];
    const float* mn = (const float*)d_in[5];
    const float* vr = (const float*)d_in[6];
    float* out = (float*)d_out;

    if (ws_size >= (size_t)(OO * CC * sizeof(__hip_bfloat16))) {
        __hip_bfloat16* Wp = (__hip_bfloat16*)d_ws;
        wperm_kernel<<<dim3((OO * CC + 255) / 256), dim3(256), 0, stream>>>(W, Wp);
        fused_main_kernel<<<dim3(NB * (LL / LT)), dim3(512), 0, stream>>>(
            x, Wp, A, gm, bt, mn, vr, out);
    } else {
        const int threadsA = NB * CC * VV * 8;
        wsum_kernel<<<dim3((threadsA + 255) / 256), dim3(256), 0, stream>>>(x, out);
        fused_fallback_kernel<<<dim3(NB * LL), dim3(256), 0, stream>>>(
            out, x, W, A, gm, bt, mn, vr, out);
    }
}